// Round 1
// baseline (14470.821 us; speedup 1.0000x reference)
//
#include <hip/hip_runtime.h>
#include <math.h>

#define DM 1024          // d_model
#define DF 4096          // d_ff
#define NE 24            // experts
#define T_TOK 4096       // tokens (B*S)
#define T2   (T_TOK*2)   // token-expert pairs
#define MT 64            // m-tile (tokens per block)
#define FCH 128          // f-chunk per block
#define MT_MAX 32        // supports up to 2048 tokens per expert
#define NFCH (DF/FCH)    // 32

// ---------------- gating ----------------

__global__ void k_transpose_gw(const float* __restrict__ gw, float* __restrict__ gwT) {
    int e = blockIdx.x;  // 0..23
    for (int d = threadIdx.x; d < DM; d += blockDim.x)
        gwT[e * DM + d] = gw[d * NE + e];
}

__global__ void k_gate(const float* __restrict__ x, const float* __restrict__ gwT,
                       const float* __restrict__ gb,
                       int* __restrict__ idx, float* __restrict__ prob) {
    int wave = threadIdx.x >> 6;
    int lane = threadIdx.x & 63;
    int t = blockIdx.x * 4 + wave;
    if (t >= T_TOK) return;
    const float* xr = x + (size_t)t * DM;
    float acc[NE];
#pragma unroll
    for (int e = 0; e < NE; e++) acc[e] = 0.f;
    for (int i = 0; i < DM / 64; i++) {
        int d = lane + i * 64;
        float xv = xr[d];
#pragma unroll
        for (int e = 0; e < NE; e++) acc[e] = fmaf(xv, gwT[e * DM + d], acc[e]);
    }
#pragma unroll
    for (int e = 0; e < NE; e++) {
        float v = acc[e];
        for (int off = 32; off >= 1; off >>= 1) v += __shfl_xor(v, off);
        acc[e] = v;
    }
    if (lane == 0) {
        float v1 = -1e30f, v2 = -1e30f;
        int i1 = -1, i2 = -1;
        for (int e = 0; e < NE; e++) {
            float s = acc[e] + gb[e];
            if (s > v1) { v2 = v1; i2 = i1; v1 = s; i1 = e; }
            else if (s > v2) { v2 = s; i2 = e; }
        }
        float e2 = expf(v2 - v1);           // <= 1, stable
        float inv = 1.f / (1.f + e2);
        idx[t * 2] = i1; idx[t * 2 + 1] = i2;
        prob[t * 2] = inv; prob[t * 2 + 1] = e2 * inv;
    }
}

// ---------------- routing ----------------

__global__ void k_zero(int* counts, int* cursors) {
    int i = threadIdx.x;
    if (i < NE) { counts[i] = 0; cursors[i] = 0; }
}

__global__ void k_count(const int* __restrict__ idx, int* counts) {
    int i = blockIdx.x * blockDim.x + threadIdx.x;
    if (i < T2) atomicAdd(&counts[idx[i]], 1);
}

__global__ void k_scan(const int* __restrict__ counts, int* offsets) {
    if (threadIdx.x == 0) {
        int s = 0;
        for (int e = 0; e < NE; e++) { offsets[e] = s; s += counts[e]; }
        offsets[NE] = s;
    }
}

__global__ void k_scatter(const int* __restrict__ idx, const float* __restrict__ prob,
                          const int* __restrict__ offsets, int* cursors,
                          int* __restrict__ slot_tok, float* __restrict__ slot_prob) {
    int i = blockIdx.x * blockDim.x + threadIdx.x;
    if (i < T2) {
        int e = idx[i];
        int pos = offsets[e] + atomicAdd(&cursors[e], 1);
        slot_tok[pos] = i >> 1;
        slot_prob[pos] = prob[i];
    }
}

// out[t] = p1*b2[e1] + p2*b2[e2]  (also serves as the zero-init of d_out)
__global__ void k_init_out(const int* __restrict__ idx, const float* __restrict__ prob,
                           const float* __restrict__ b2, float* __restrict__ out) {
    int t = blockIdx.x;
    int e1 = idx[t * 2], e2 = idx[t * 2 + 1];
    float p1 = prob[t * 2], p2 = prob[t * 2 + 1];
    const float* ba = b2 + (size_t)e1 * DM;
    const float* bb = b2 + (size_t)e2 * DM;
    float* o = out + (size_t)t * DM;
    for (int d = threadIdx.x; d < DM; d += blockDim.x)
        o[d] = p1 * ba[d] + p2 * bb[d];
}

// ---------------- fused expert FFN ----------------
// block: 256 threads; handles (expert e, m-tile of 64 tokens, f-chunk of 128)
// phase1: H[64][128] = gelu(X[64][1024] @ W1e[1024][fc] + b1)
// phase2: for each 128-col out chunk: atomicAdd(out, prob * (H @ W2e[fc][dc]))

__global__ __launch_bounds__(256)
void k_ffn(const float* __restrict__ x, const float* __restrict__ w1,
           const float* __restrict__ b1, const float* __restrict__ w2,
           const int* __restrict__ counts, const int* __restrict__ offsets,
           const int* __restrict__ slot_tok, const float* __restrict__ slot_prob,
           float* __restrict__ out) {
    const int e  = blockIdx.x / MT_MAX;
    const int mt = blockIdx.x % MT_MAX;
    const int ne = counts[e];
    const int m0 = mt * MT;
    if (m0 >= ne) return;
    const int fc0 = blockIdx.y * FCH;
    const int rows = min(MT, ne - m0);

    __shared__ int   toks[MT];
    __shared__ float pr[MT];
    __shared__ float Xs[16][MT + 1];
    __shared__ float Ws[16][FCH];        // reused for W1 then W2 staging
    __shared__ float Hs[MT][FCH + 1];

    const int tid = threadIdx.x;
    if (tid < MT) {
        int m = tid;
        int src = offsets[e] + m0 + ((m < rows) ? m : 0);
        toks[m] = slot_tok[src];
        pr[m]   = (m < rows) ? slot_prob[src] : 0.f;
    }
    __syncthreads();

    const float* w1e = w1 + (size_t)e * DM * DF;
    const float* w2e = w2 + (size_t)e * DF * DM;

    const int tx = tid & 31;        // 0..31
    const int ty = tid >> 5;        // 0..7
    const int lm = tid & 63;        // token row for X loads
    const int lg = tid >> 6;        // 0..3  d-subgroup (4 d's each)
    const int wdd = tid >> 4;       // 0..15 row for W loads
    const int wf8 = (tid & 15) * 8; // col*8 for W loads

    float acc[8][4];
#pragma unroll
    for (int r = 0; r < 8; r++)
#pragma unroll
        for (int c = 0; c < 4; c++) acc[r][c] = 0.f;

    const float* xrow = x + (size_t)toks[lm] * DM;

    for (int d0 = 0; d0 < DM; d0 += 16) {
        float4 xv = *(const float4*)(xrow + d0 + lg * 4);
        Xs[lg * 4 + 0][lm] = xv.x;
        Xs[lg * 4 + 1][lm] = xv.y;
        Xs[lg * 4 + 2][lm] = xv.z;
        Xs[lg * 4 + 3][lm] = xv.w;
        const float* wr = w1e + (size_t)(d0 + wdd) * DF + fc0 + wf8;
        float4 wa = *(const float4*)(wr);
        float4 wb = *(const float4*)(wr + 4);
        *(float4*)&Ws[wdd][wf8]     = wa;
        *(float4*)&Ws[wdd][wf8 + 4] = wb;
        __syncthreads();
#pragma unroll
        for (int dd = 0; dd < 16; dd++) {
            float av[8], bv[4];
#pragma unroll
            for (int r = 0; r < 8; r++) av[r] = Xs[dd][r * 8 + ty];
#pragma unroll
            for (int c = 0; c < 4; c++) bv[c] = Ws[dd][c * 32 + tx];
#pragma unroll
            for (int r = 0; r < 8; r++)
#pragma unroll
                for (int c = 0; c < 4; c++)
                    acc[r][c] = fmaf(av[r], bv[c], acc[r][c]);
        }
        __syncthreads();
    }

    // bias + exact gelu -> Hs
#pragma unroll
    for (int c = 0; c < 4; c++) {
        float bb = b1[(size_t)e * DF + fc0 + c * 32 + tx];
#pragma unroll
        for (int r = 0; r < 8; r++) {
            float h = acc[r][c] + bb;
            h = 0.5f * h * (1.f + erff(h * 0.70710678118654752f));
            Hs[r * 8 + ty][c * 32 + tx] = h;
        }
    }
    __syncthreads();

    for (int dc0 = 0; dc0 < DM; dc0 += 128) {
        float acc2[8][4];
#pragma unroll
        for (int r = 0; r < 8; r++)
#pragma unroll
            for (int c = 0; c < 4; c++) acc2[r][c] = 0.f;

        for (int k0 = 0; k0 < FCH; k0 += 16) {
            const float* wr2 = w2e + (size_t)(fc0 + k0 + wdd) * DM + dc0 + wf8;
            float4 wa = *(const float4*)(wr2);
            float4 wb = *(const float4*)(wr2 + 4);
            __syncthreads();   // protect Ws from previous sub-iteration's readers
            *(float4*)&Ws[wdd][wf8]     = wa;
            *(float4*)&Ws[wdd][wf8 + 4] = wb;
            __syncthreads();
#pragma unroll
            for (int kk = 0; kk < 16; kk++) {
                float av[8], bv[4];
#pragma unroll
                for (int r = 0; r < 8; r++) av[r] = Hs[r * 8 + ty][k0 + kk];
#pragma unroll
                for (int c = 0; c < 4; c++) bv[c] = Ws[kk][c * 32 + tx];
#pragma unroll
                for (int r = 0; r < 8; r++)
#pragma unroll
                    for (int c = 0; c < 4; c++)
                        acc2[r][c] = fmaf(av[r], bv[c], acc2[r][c]);
            }
        }
#pragma unroll
        for (int r = 0; r < 8; r++) {
            int m = r * 8 + ty;
            if (m < rows) {
                float p = pr[m];
                float* orow = out + (size_t)toks[m] * DM + dc0;
#pragma unroll
                for (int c = 0; c < 4; c++)
                    atomicAdd(&orow[c * 32 + tx], p * acc2[r][c]);
            }
        }
    }
}

// ---------------- launch ----------------

extern "C" void kernel_launch(void* const* d_in, const int* in_sizes, int n_in,
                              void* d_out, int out_size, void* d_ws, size_t ws_size,
                              hipStream_t stream) {
    const float* x   = (const float*)d_in[0];
    const float* gw  = (const float*)d_in[1];
    const float* gb  = (const float*)d_in[2];
    const float* w1  = (const float*)d_in[3];
    const float* b1  = (const float*)d_in[4];
    const float* w2  = (const float*)d_in[5];
    const float* b2  = (const float*)d_in[6];
    float* out = (float*)d_out;

    size_t off = 0;
    auto alloc = [&](size_t bytes) {
        void* p = (char*)d_ws + off;
        off += (bytes + 255) & ~(size_t)255;
        return p;
    };
    float* gwT       = (float*)alloc(NE * DM * sizeof(float));
    int*   idx       = (int*)alloc(T2 * sizeof(int));
    float* prob      = (float*)alloc(T2 * sizeof(float));
    int*   counts    = (int*)alloc(32 * sizeof(int));
    int*   offsets   = (int*)alloc(32 * sizeof(int));
    int*   cursors   = (int*)alloc(32 * sizeof(int));
    int*   slot_tok  = (int*)alloc(T2 * sizeof(int));
    float* slot_prob = (float*)alloc(T2 * sizeof(float));

    k_transpose_gw<<<NE, 256, 0, stream>>>(gw, gwT);
    k_gate<<<T_TOK / 4, 256, 0, stream>>>(x, gwT, gb, idx, prob);
    k_zero<<<1, 64, 0, stream>>>(counts, cursors);
    k_count<<<T2 / 256, 256, 0, stream>>>(idx, counts);
    k_scan<<<1, 64, 0, stream>>>(counts, offsets);
    k_scatter<<<T2 / 256, 256, 0, stream>>>(idx, prob, offsets, cursors, slot_tok, slot_prob);
    k_init_out<<<T_TOK, 256, 0, stream>>>(idx, prob, b2, out);

    dim3 g(NE * MT_MAX, NFCH);
    k_ffn<<<g, 256, 0, stream>>>(x, w1, b1, w2, counts, offsets, slot_tok, slot_prob, out);
}

// Round 2
// 789.306 us; speedup vs baseline: 18.3336x; 18.3336x over previous
//
#include <hip/hip_runtime.h>
#include <math.h>

#define DM 1024
#define DF 4096
#define NE 24
#define T_TOK 4096
#define T2 (T_TOK*2)

#define BM 128
#define BN 128
#define BK 64
#define LDK 72          // padded LDS row stride in shorts (144 B)
#define MTILES 8        // max 1024 tokens per expert (measured ~341 +/- 20)
#define SPLITK 2
#define KSPL (DF / SPLITK)

typedef __attribute__((ext_vector_type(4))) float f32x4;
typedef __attribute__((ext_vector_type(8))) short s16x8;

// exact RNE fp32 -> bf16 (finite inputs)
static __device__ __forceinline__ unsigned short f2bf(float f) {
    unsigned int u = __float_as_uint(f);
    unsigned int r = u + 0x7fffu + ((u >> 16) & 1u);
    return (unsigned short)(r >> 16);
}

// ---------------- gating ----------------

__global__ void k_transpose_gw(const float* __restrict__ gw, float* __restrict__ gwT) {
    int e = blockIdx.x;
    for (int d = threadIdx.x; d < DM; d += blockDim.x)
        gwT[e * DM + d] = gw[d * NE + e];
}

__global__ void k_gate(const float* __restrict__ x, const float* __restrict__ gwT,
                       const float* __restrict__ gb,
                       int* __restrict__ idx, float* __restrict__ prob) {
    int wave = threadIdx.x >> 6;
    int lane = threadIdx.x & 63;
    int t = blockIdx.x * 4 + wave;
    if (t >= T_TOK) return;
    const float* xr = x + (size_t)t * DM;
    float acc[NE];
#pragma unroll
    for (int e = 0; e < NE; e++) acc[e] = 0.f;
    for (int i = 0; i < DM / 64; i++) {
        int d = lane + i * 64;
        float xv = xr[d];
#pragma unroll
        for (int e = 0; e < NE; e++) acc[e] = fmaf(xv, gwT[e * DM + d], acc[e]);
    }
#pragma unroll
    for (int e = 0; e < NE; e++) {
        float v = acc[e];
        for (int off = 32; off >= 1; off >>= 1) v += __shfl_xor(v, off);
        acc[e] = v;
    }
    if (lane == 0) {
        float v1 = -1e30f, v2 = -1e30f;
        int i1 = -1, i2 = -1;
        for (int e = 0; e < NE; e++) {
            float s = acc[e] + gb[e];
            if (s > v1) { v2 = v1; i2 = i1; v1 = s; i1 = e; }
            else if (s > v2) { v2 = s; i2 = e; }
        }
        float e2 = expf(v2 - v1);
        float inv = 1.f / (1.f + e2);
        idx[t * 2] = i1; idx[t * 2 + 1] = i2;
        prob[t * 2] = inv; prob[t * 2 + 1] = e2 * inv;
    }
}

// ---------------- routing ----------------

__global__ void k_zero(int* counts, int* cursors) {
    int i = threadIdx.x;
    if (i < NE) { counts[i] = 0; cursors[i] = 0; }
}

__global__ void k_count(const int* __restrict__ idx, int* counts) {
    int i = blockIdx.x * blockDim.x + threadIdx.x;
    if (i < T2) atomicAdd(&counts[idx[i]], 1);
}

__global__ void k_scan(const int* __restrict__ counts, int* offsets) {
    if (threadIdx.x == 0) {
        int s = 0;
        for (int e = 0; e < NE; e++) { offsets[e] = s; s += counts[e]; }
        offsets[NE] = s;
    }
}

__global__ void k_scatter(const int* __restrict__ idx, const float* __restrict__ prob,
                          const int* __restrict__ offsets, int* cursors,
                          int* __restrict__ slot_tok, float* __restrict__ slot_prob) {
    int i = blockIdx.x * blockDim.x + threadIdx.x;
    if (i < T2) {
        int e = idx[i];
        int pos = offsets[e] + atomicAdd(&cursors[e], 1);
        slot_tok[pos] = i >> 1;
        slot_prob[pos] = prob[i];
    }
}

// gather routed token rows into dense bf16 slot-major matrix Xg[slot][DM]
__global__ void k_gather(const float* __restrict__ x, const int* __restrict__ slot_tok,
                         unsigned short* __restrict__ Xg) {
    int s = blockIdx.x;
    int tok = slot_tok[s];
    const float4* src = (const float4*)(x + (size_t)tok * DM);
    ushort4* dst = (ushort4*)(Xg + (size_t)s * DM);
    for (int i = threadIdx.x; i < DM / 4; i += blockDim.x) {
        float4 v = src[i];
        ushort4 o;
        o.x = f2bf(v.x); o.y = f2bf(v.y); o.z = f2bf(v.z); o.w = f2bf(v.w);
        dst[i] = o;
    }
}

// out[t] = p1*b2[e1] + p2*b2[e2]  (zero-init + bias combine)
__global__ void k_init_out(const int* __restrict__ idx, const float* __restrict__ prob,
                           const float* __restrict__ b2, float* __restrict__ out) {
    int t = blockIdx.x;
    int e1 = idx[t * 2], e2 = idx[t * 2 + 1];
    float p1 = prob[t * 2], p2 = prob[t * 2 + 1];
    const float* ba = b2 + (size_t)e1 * DM;
    const float* bb = b2 + (size_t)e2 * DM;
    float* o = out + (size_t)t * DM;
    for (int d = threadIdx.x; d < DM; d += blockDim.x)
        o[d] = p1 * ba[d] + p2 * bb[d];
}

// ---------------- FFN1: H = gelu(Xg @ W1e + b1)  [bf16 MFMA] ----------------
// grid: (DF/BN, NE*MTILES); 256 threads = 4 waves (2x2), tile 128x128, BK=64

__global__ __launch_bounds__(256)
void k_ffn1(const unsigned short* __restrict__ Xg, const float* __restrict__ w1,
            const float* __restrict__ b1, const int* __restrict__ counts,
            const int* __restrict__ offsets, unsigned short* __restrict__ H) {
    const int emt = blockIdx.y;
    const int e = emt / MTILES, mt = emt % MTILES;
    const int ne = counts[e];
    const int m0 = mt * BM;
    if (m0 >= ne) return;
    const int rows = min(BM, ne - m0);
    const int n0 = blockIdx.x * BN;
    const int slotbase = offsets[e] + m0;

    __shared__ unsigned short As[BM * LDK];
    __shared__ unsigned short Bs[BN * LDK];

    const int tid  = threadIdx.x;
    const int lane = tid & 63;
    const int wid  = tid >> 6;
    const int wm   = wid >> 1, wn = wid & 1;

    const float* w1e = w1 + (size_t)e * DM * DF;

    f32x4 acc[4][4];
#pragma unroll
    for (int a = 0; a < 4; a++)
#pragma unroll
        for (int b = 0; b < 4; b++) acc[a][b] = (f32x4)0.f;

    // A staging: thread -> row am, 16B chunks ac..ac+3
    const int am = tid >> 1;
    const int ac = (tid & 1) * 4;
    const unsigned short* asrc = Xg + (size_t)(slotbase + am) * DM + ac * 8;
    unsigned short* adst = &As[am * LDK + ac * 8];

    // B staging: thread -> col bn, k-range bkh..bkh+31 (coalesced across lanes)
    const int bn  = tid & 127;
    const int bkh = (tid >> 7) * 32;
    unsigned short* bdst = &Bs[bn * LDK + bkh];

    for (int k0 = 0; k0 < DM; k0 += BK) {
        int4 av[4];
#pragma unroll
        for (int j = 0; j < 4; j++)
            av[j] = *(const int4*)(asrc + k0 + j * 8);
        s16x8 bp[4];
#pragma unroll
        for (int j = 0; j < 4; j++) {
            float t[8];
#pragma unroll
            for (int i = 0; i < 8; i++)
                t[i] = w1e[(size_t)(k0 + bkh + j * 8 + i) * DF + n0 + bn];
#pragma unroll
            for (int i = 0; i < 8; i++) bp[j][i] = (short)f2bf(t[i]);
        }
        __syncthreads();
#pragma unroll
        for (int j = 0; j < 4; j++)
            *(int4*)(adst + j * 8) = av[j];
#pragma unroll
        for (int j = 0; j < 4; j++)
            *(s16x8*)(bdst + j * 8) = bp[j];
        __syncthreads();
#pragma unroll
        for (int ks = 0; ks < 2; ks++) {
            const int ko = ks * 32 + (lane >> 4) * 8;
            s16x8 af[4], bfr[4];
#pragma unroll
            for (int f = 0; f < 4; f++)
                af[f] = *(const s16x8*)&As[(wm * 64 + f * 16 + (lane & 15)) * LDK + ko];
#pragma unroll
            for (int f = 0; f < 4; f++)
                bfr[f] = *(const s16x8*)&Bs[(wn * 64 + f * 16 + (lane & 15)) * LDK + ko];
#pragma unroll
            for (int fm = 0; fm < 4; fm++)
#pragma unroll
                for (int fn = 0; fn < 4; fn++)
                    acc[fm][fn] = __builtin_amdgcn_mfma_f32_16x16x32_bf16(
                        af[fm], bfr[fn], acc[fm][fn], 0, 0, 0);
        }
    }

    const float* b1e = b1 + (size_t)e * DF;
#pragma unroll
    for (int fm = 0; fm < 4; fm++) {
        const int mrow = wm * 64 + fm * 16 + ((lane >> 4) << 2);
#pragma unroll
        for (int fn = 0; fn < 4; fn++) {
            const int ncol = n0 + wn * 64 + fn * 16 + (lane & 15);
            const float bb = b1e[ncol];
#pragma unroll
            for (int r = 0; r < 4; r++) {
                const int m = mrow + r;
                if (m < rows) {
                    float h = acc[fm][fn][r] + bb;
                    h = 0.5f * h * (1.f + erff(h * 0.70710678118654752f));
                    H[(size_t)(slotbase + m) * DF + ncol] = f2bf(h);
                }
            }
        }
    }
}

// ---------------- FFN2: out += p * (H @ W2e)  [bf16 MFMA, split-K] ----------------
// grid: ((DM/BN)*SPLITK, NE*MTILES)

__global__ __launch_bounds__(256)
void k_ffn2(const unsigned short* __restrict__ H, const float* __restrict__ w2,
            const int* __restrict__ counts, const int* __restrict__ offsets,
            const int* __restrict__ slot_tok, const float* __restrict__ slot_prob,
            float* __restrict__ out) {
    const int emt = blockIdx.y;
    const int e = emt / MTILES, mt = emt % MTILES;
    const int ne = counts[e];
    const int m0 = mt * BM;
    if (m0 >= ne) return;
    const int rows = min(BM, ne - m0);
    const int nch = blockIdx.x & ((DM / BN) - 1);
    const int ksl = blockIdx.x >> 3;
    const int n0 = nch * BN;
    const int slotbase = offsets[e] + m0;

    __shared__ unsigned short As[BM * LDK];
    __shared__ unsigned short Bs[BN * LDK];
    __shared__ int   toksh[BM];
    __shared__ float prh[BM];

    const int tid  = threadIdx.x;
    const int lane = tid & 63;
    const int wid  = tid >> 6;
    const int wm   = wid >> 1, wn = wid & 1;

    if (tid < BM) {
        int src = slotbase + ((tid < rows) ? tid : 0);
        toksh[tid] = slot_tok[src];
        prh[tid]   = (tid < rows) ? slot_prob[src] : 0.f;
    }

    const float* w2e = w2 + (size_t)e * DF * DM;

    f32x4 acc[4][4];
#pragma unroll
    for (int a = 0; a < 4; a++)
#pragma unroll
        for (int b = 0; b < 4; b++) acc[a][b] = (f32x4)0.f;

    const int am = tid >> 1;
    const int ac = (tid & 1) * 4;
    const unsigned short* asrc = H + (size_t)(slotbase + am) * DF + ac * 8;
    unsigned short* adst = &As[am * LDK + ac * 8];

    const int bn  = tid & 127;
    const int bkh = (tid >> 7) * 32;
    unsigned short* bdst = &Bs[bn * LDK + bkh];

    const int kbeg = ksl * KSPL;
    for (int k0 = kbeg; k0 < kbeg + KSPL; k0 += BK) {
        int4 av[4];
#pragma unroll
        for (int j = 0; j < 4; j++)
            av[j] = *(const int4*)(asrc + k0 + j * 8);
        s16x8 bp[4];
#pragma unroll
        for (int j = 0; j < 4; j++) {
            float t[8];
#pragma unroll
            for (int i = 0; i < 8; i++)
                t[i] = w2e[(size_t)(k0 + bkh + j * 8 + i) * DM + n0 + bn];
#pragma unroll
            for (int i = 0; i < 8; i++) bp[j][i] = (short)f2bf(t[i]);
        }
        __syncthreads();
#pragma unroll
        for (int j = 0; j < 4; j++)
            *(int4*)(adst + j * 8) = av[j];
#pragma unroll
        for (int j = 0; j < 4; j++)
            *(s16x8*)(bdst + j * 8) = bp[j];
        __syncthreads();
#pragma unroll
        for (int ks = 0; ks < 2; ks++) {
            const int ko = ks * 32 + (lane >> 4) * 8;
            s16x8 af[4], bfr[4];
#pragma unroll
            for (int f = 0; f < 4; f++)
                af[f] = *(const s16x8*)&As[(wm * 64 + f * 16 + (lane & 15)) * LDK + ko];
#pragma unroll
            for (int f = 0; f < 4; f++)
                bfr[f] = *(const s16x8*)&Bs[(wn * 64 + f * 16 + (lane & 15)) * LDK + ko];
#pragma unroll
            for (int fm = 0; fm < 4; fm++)
#pragma unroll
                for (int fn = 0; fn < 4; fn++)
                    acc[fm][fn] = __builtin_amdgcn_mfma_f32_16x16x32_bf16(
                        af[fm], bfr[fn], acc[fm][fn], 0, 0, 0);
        }
    }

#pragma unroll
    for (int fm = 0; fm < 4; fm++) {
        const int mrow = wm * 64 + fm * 16 + ((lane >> 4) << 2);
#pragma unroll
        for (int fn = 0; fn < 4; fn++) {
            const int ncol = n0 + wn * 64 + fn * 16 + (lane & 15);
#pragma unroll
            for (int r = 0; r < 4; r++) {
                const int m = mrow + r;
                if (m < rows)
                    atomicAdd(&out[(size_t)toksh[m] * DM + ncol], acc[fm][fn][r] * prh[m]);
            }
        }
    }
}

// ---------------- launch ----------------

extern "C" void kernel_launch(void* const* d_in, const int* in_sizes, int n_in,
                              void* d_out, int out_size, void* d_ws, size_t ws_size,
                              hipStream_t stream) {
    const float* x   = (const float*)d_in[0];
    const float* gw  = (const float*)d_in[1];
    const float* gb  = (const float*)d_in[2];
    const float* w1  = (const float*)d_in[3];
    const float* b1  = (const float*)d_in[4];
    const float* w2  = (const float*)d_in[5];
    const float* b2  = (const float*)d_in[6];
    float* out = (float*)d_out;

    size_t off = 0;
    auto alloc = [&](size_t bytes) {
        void* p = (char*)d_ws + off;
        off += (bytes + 255) & ~(size_t)255;
        return p;
    };
    float* gwT       = (float*)alloc(NE * DM * sizeof(float));
    int*   idx       = (int*)alloc(T2 * sizeof(int));
    float* prob      = (float*)alloc(T2 * sizeof(float));
    int*   counts    = (int*)alloc(32 * sizeof(int));
    int*   offsets   = (int*)alloc(32 * sizeof(int));
    int*   cursors   = (int*)alloc(32 * sizeof(int));
    int*   slot_tok  = (int*)alloc(T2 * sizeof(int));
    float* slot_prob = (float*)alloc(T2 * sizeof(float));
    unsigned short* Xg = (unsigned short*)alloc((size_t)(T2 + BM) * DM * sizeof(unsigned short));
    unsigned short* Hb = (unsigned short*)alloc((size_t)(T2 + BM) * DF * sizeof(unsigned short));

    k_transpose_gw<<<NE, 256, 0, stream>>>(gw, gwT);
    k_gate<<<T_TOK / 4, 256, 0, stream>>>(x, gwT, gb, idx, prob);
    k_zero<<<1, 64, 0, stream>>>(counts, cursors);
    k_count<<<T2 / 256, 256, 0, stream>>>(idx, counts);
    k_scan<<<1, 64, 0, stream>>>(counts, offsets);
    k_scatter<<<T2 / 256, 256, 0, stream>>>(idx, prob, offsets, cursors, slot_tok, slot_prob);
    k_gather<<<T2, 256, 0, stream>>>(x, slot_tok, Xg);
    k_init_out<<<T_TOK, 256, 0, stream>>>(idx, prob, b2, out);

    dim3 g1(DF / BN, NE * MTILES);
    k_ffn1<<<g1, 256, 0, stream>>>(Xg, w1, b1, counts, offsets, Hb);
    dim3 g2((DM / BN) * SPLITK, NE * MTILES);
    k_ffn2<<<g2, 256, 0, stream>>>(Hb, w2, counts, offsets, slot_tok, slot_prob, out);
}